// Round 4
// baseline (351.491 us; speedup 1.0000x reference)
//
#include <hip/hip_runtime.h>
#include <hip/hip_cooperative_groups.h>

namespace cg = cooperative_groups;

#define IN_DIM  4096
#define OUT_DIM 11008
#define NSUB    1376
#define KSQ     256
#define DSUB    8
#define BATCH   32

#define DTILE   8                    // subspaces per tile
#define NTILE   64                   // output cols per tile
#define KC      64                   // k per chunk
#define KSPLIT  16                   // k-tiles per output column
#define KPB     (IN_DIM / KSPLIT)    // 256
#define NCHUNK  (KPB / KC)           // 4
#define NBLK    (OUT_DIM / NTILE)    // 172
#define NTILES  (NBLK * KSPLIT)      // 2752 (ordered kblk-inner: tile = nblk*16+kblk)

typedef unsigned short ushort_t;
typedef unsigned int   uint_t;
typedef unsigned char  uchar_t;
typedef __attribute__((ext_vector_type(8))) short bf16x8;
typedef __attribute__((ext_vector_type(4))) float f32x4;

// workspace layout (bytes)
#define VEC_N    (NSUB * KSQ * DSUB)              // 2818048 floats
#define XBF_OFF  (VEC_N * 2)                      // xbf (bf16 x)
#define IDXT_OFF (XBF_OFF + BATCH * IN_DIM * 2)   // idx8T [NSUB][IN_DIM] u8
#define SLAB_OFF (IDXT_OFF + NSUB * IN_DIM)       // f32 slabs [KSPLIT][BATCH][OUT_DIM]

#define SMEM_BYTES 40960                          // 32 KB sV4 + 8 KB sW32 (union w/ sT)
#define IDXT_TILES ((IN_DIM / 128) * (NSUB / 32)) // 1376

__device__ __forceinline__ ushort_t f2bf(float f) {
    union { float f; uint_t u; } a; a.f = f;
    uint_t u = a.u;
    u += 0x7fffu + ((u >> 16) & 1u);   // round-to-nearest-even
    return (ushort_t)(u >> 16);
}

// ---- phase 1: bf16-pack codebook + x; transpose idx -> u8 [d][k] ----------
__device__ __forceinline__ void phase_prep(
    const float* __restrict__ x, const float* __restrict__ vecs,
    const int* __restrict__ idx,
    uint_t* __restrict__ vbf, uint_t* __restrict__ xbf,
    uchar_t* __restrict__ idx8T, char* smem, int t, int bid, int G)
{
    const int g = bid * 256 + t, stride = G * 256;

    for (int i = g; i < VEC_N / 4; i += stride) {
        float4 v = ((const float4*)vecs)[i];
        uint2 o;
        o.x = (uint_t)f2bf(v.x) | ((uint_t)f2bf(v.y) << 16);
        o.y = (uint_t)f2bf(v.z) | ((uint_t)f2bf(v.w) << 16);
        ((uint2*)vbf)[i] = o;
    }
    for (int i = g; i < BATCH * IN_DIM / 4; i += stride) {
        float4 v = ((const float4*)x)[i];
        uint2 o;
        o.x = (uint_t)f2bf(v.x) | ((uint_t)f2bf(v.y) << 16);
        o.y = (uint_t)f2bf(v.z) | ((uint_t)f2bf(v.w) << 16);
        ((uint2*)xbf)[i] = o;
    }

    uchar_t (*sT)[144] = (uchar_t (*)[144])smem;
    for (int tile = bid; tile < IDXT_TILES; tile += G) {
        const int k0 = (tile & 31) * 128, d0 = (tile >> 5) * 32;
        __syncthreads();                 // protect sT reuse across iterations
        #pragma unroll
        for (int p = 0; p < 16; ++p) {
            int f = p * 256 + t, kk = f >> 5, dd = f & 31;
            sT[dd][kk] = (uchar_t)idx[(size_t)(k0 + kk) * NSUB + d0 + dd];
        }
        __syncthreads();
        int dd = t >> 3, seg = t & 7;
        uint4 v = *(const uint4*)&sT[dd][seg * 16];
        *(uint4*)&idx8T[(size_t)(d0 + dd) * IN_DIM + k0 + seg * 16] = v;
    }
}

// ---- phase 2: barrier-free, wave-independent PQ-GEMM over tile range ------
__device__ __forceinline__ void phase_main(
    const ushort_t* __restrict__ xbfu, const uint4* __restrict__ vbf4,
    const uchar_t* __restrict__ idx8T, float* __restrict__ slab,
    char* smem, int t, int bid, int G)
{
    uint4*  sV4  = (uint4*)smem;           // 32 KB: per-wave 2x256 codewords
    uint_t* sW32 = (uint_t*)(smem + 32768); //  8 KB: per-wave 16 rows x 64 k (swizzled)

    const int w = t >> 6, lane = t & 63;
    const int l15 = lane & 15, l4 = lane >> 4, dl = lane >> 5, q = lane & 31;

    const int tt0 = (int)(((long)bid * NTILES) / G);
    const int tt1 = (int)(((long)(bid + 1) * NTILES) / G);
    int cur_nblk = -1;

    for (int tile = tt0; tile < tt1; ++tile) {
        const int nblk = tile >> 4, kblk = tile & 15;
        const int d0 = nblk * DTILE, kbase = kblk * KPB;

        // stage codebook slice only when nblk changes (kblk-inner tile order)
        if (nblk != cur_nblk) {
            cur_nblk = nblk;
            const size_t src0 = (size_t)(d0 + w * 2) * KSQ;   // uint4 units
            #pragma unroll
            for (int h = 0; h < 2; ++h) {
                uint4 vst[4];
                #pragma unroll
                for (int p = 0; p < 4; ++p)
                    vst[p] = vbf4[src0 + (h * 4 + p) * 64 + lane];
                #pragma unroll
                for (int p = 0; p < 4; ++p)
                    sV4[w * 512 + (h * 4 + p) * 64 + lane] = vst[p];
            }
        }

        // A fragments for the whole KPB
        bf16x8 A[2][8];
        #pragma unroll
        for (int mt = 0; mt < 2; ++mt)
            #pragma unroll
            for (int kk = 0; kk < 8; ++kk)
                A[mt][kk] = *(const bf16x8*)
                    &xbfu[(size_t)(mt * 16 + l15) * IN_DIM + kbase + kk * 32 + l4 * 8];

        // idx bytes
        const uchar_t* idxrow = idx8T + (size_t)(d0 + w * 2 + dl) * IN_DIM + kbase;
        uint_t bb[NCHUNK];
        #pragma unroll
        for (int c = 0; c < NCHUNK; ++c)
            bb[c] = *(const ushort_t*)&idxrow[c * KC + q * 2];

        f32x4 acc[2];
        acc[0] = (f32x4)0.0f; acc[1] = (f32x4)0.0f;
        const int vbase = w * 512 + dl * 256;
        const int Rbase = (w * 16 + dl * 8) * 32;

        #pragma unroll
        for (int c = 0; c < NCHUNK; ++c) {
            uint4 g0 = sV4[vbase + (bb[c] & 255)];
            uint4 g1 = sV4[vbase + (bb[c] >> 8)];

            #pragma unroll
            for (int j = 0; j < 8; ++j) {
                const uint_t sel = (j & 1) ? 0x07060302u : 0x05040100u;
                uint_t a0 = (j >> 1) == 0 ? g0.x : (j >> 1) == 1 ? g0.y : (j >> 1) == 2 ? g0.z : g0.w;
                uint_t a1 = (j >> 1) == 0 ? g1.x : (j >> 1) == 1 ? g1.y : (j >> 1) == 2 ? g1.z : g1.w;
                uint_t wv = __builtin_amdgcn_perm(a1, a0, sel);   // [k even | k odd<<16]
                int dw = ((((q >> 2) ^ j) << 2) | (q & 3));
                sW32[Rbase + j * 32 + dw] = wv;
            }

            #pragma unroll
            for (int kq = 0; kq < 2; ++kq) {
                int u16 = (kq * 4 + l4) ^ (l15 & 7);
                bf16x8 B = *(const bf16x8*)
                    ((const char*)sW32 + (w * 16 + l15) * 128 + u16 * 16);
                #pragma unroll
                for (int mt = 0; mt < 2; ++mt)
                    acc[mt] = __builtin_amdgcn_mfma_f32_16x16x32_bf16(
                        A[mt][c * 2 + kq], B, acc[mt], 0, 0, 0);
            }
        }

        float* sl = slab + (size_t)kblk * BATCH * OUT_DIM;
        const int col = nblk * NTILE + w * 16 + l15;
        #pragma unroll
        for (int mt = 0; mt < 2; ++mt)
            #pragma unroll
            for (int r = 0; r < 4; ++r)
                sl[(size_t)(mt * 16 + l4 * 4 + r) * OUT_DIM + col] = acc[mt][r];
    }
}

// ---- phase 3: out = bias + sum_k slabs ------------------------------------
__device__ __forceinline__ void phase_reduce(
    const float* __restrict__ slab, const float* __restrict__ bias,
    float* __restrict__ out, int g, int stride)
{
    for (int i = g; i < BATCH * OUT_DIM / 4; i += stride) {
        int m = i / (OUT_DIM / 4), n4 = i - m * (OUT_DIM / 4);
        float4 s = ((const float4*)bias)[n4];
        #pragma unroll
        for (int kb = 0; kb < KSPLIT; ++kb) {
            float4 v = ((const float4*)slab)[(size_t)(kb * BATCH + m) * (OUT_DIM / 4) + n4];
            s.x += v.x; s.y += v.y; s.z += v.z; s.w += v.w;
        }
        ((float4*)out)[i] = s;
    }
}

// ---- fused cooperative kernel ---------------------------------------------
__global__ __launch_bounds__(256) void pq_all(
    const float* __restrict__ x, const float* __restrict__ vecs,
    const float* __restrict__ bias, const int* __restrict__ idx,
    uint_t* __restrict__ vbf, uint_t* __restrict__ xbf,
    uchar_t* __restrict__ idx8T, float* __restrict__ slab,
    float* __restrict__ out)
{
    extern __shared__ __align__(16) char smem[];
    const int t = threadIdx.x, bid = blockIdx.x, G = gridDim.x;

    phase_prep(x, vecs, idx, vbf, xbf, idx8T, smem, t, bid, G);
    __threadfence();
    cg::this_grid().sync();

    phase_main((const ushort_t*)xbf, (const uint4*)vbf, idx8T, slab, smem, t, bid, G);
    __threadfence();
    cg::this_grid().sync();

    phase_reduce(slab, bias, out, bid * 256 + t, G * 256);
}

// ---- fallback wrappers (non-cooperative path) -----------------------------
__global__ __launch_bounds__(256) void pq_p1(
    const float* __restrict__ x, const float* __restrict__ vecs,
    const int* __restrict__ idx, uint_t* __restrict__ vbf,
    uint_t* __restrict__ xbf, uchar_t* __restrict__ idx8T)
{
    extern __shared__ __align__(16) char smem[];
    phase_prep(x, vecs, idx, vbf, xbf, idx8T, smem, threadIdx.x, blockIdx.x, gridDim.x);
}

__global__ __launch_bounds__(256) void pq_p2(
    const ushort_t* __restrict__ xbfu, const uint4* __restrict__ vbf4,
    const uchar_t* __restrict__ idx8T, float* __restrict__ slab)
{
    extern __shared__ __align__(16) char smem[];
    phase_main(xbfu, vbf4, idx8T, slab, smem, threadIdx.x, blockIdx.x, gridDim.x);
}

__global__ __launch_bounds__(256) void pq_p3(
    const float* __restrict__ slab, const float* __restrict__ bias,
    float* __restrict__ out)
{
    phase_reduce(slab, bias, out, blockIdx.x * 256 + threadIdx.x, gridDim.x * 256);
}

extern "C" void kernel_launch(void* const* d_in, const int* in_sizes, int n_in,
                              void* d_out, int out_size, void* d_ws, size_t ws_size,
                              hipStream_t stream) {
    const float* x    = (const float*)d_in[0];
    const float* vecs = (const float*)d_in[1];
    const float* bias = (const float*)d_in[2];
    const int*   idx  = (const int*)d_in[3];
    float* out = (float*)d_out;

    uint_t*  vbf   = (uint_t*)d_ws;
    uint_t*  xbf   = (uint_t*)((char*)d_ws + XBF_OFF);
    uchar_t* idx8T = (uchar_t*)((char*)d_ws + IDXT_OFF);
    float*   slab  = (float*)((char*)d_ws + SLAB_OFF);

    static int G = 0;
    if (G == 0) {
        int bpc = 0;
        if (hipOccupancyMaxActiveBlocksPerMultiprocessor(
                &bpc, pq_all, 256, (size_t)SMEM_BYTES) != hipSuccess || bpc < 1)
            bpc = 2;
        if (bpc > 4) bpc = 4;            // LDS cap: 160 KB / 40 KB
        G = bpc * 256;                   // MI355X: 256 CUs
    }

    void* args[] = {(void*)&x, (void*)&vecs, (void*)&bias, (void*)&idx,
                    (void*)&vbf, (void*)&xbf, (void*)&idx8T, (void*)&slab,
                    (void*)&out};
    hipError_t e = hipLaunchCooperativeKernel(
        reinterpret_cast<const void*>(pq_all), dim3(G), dim3(256),
        args, (unsigned)SMEM_BYTES, stream);

    if (e != hipSuccess) {
        // fallback: 3 ordinary dispatches (stream-ordered)
        pq_p1<<<2048, 256, SMEM_BYTES, stream>>>(x, vecs, idx, vbf, xbf, idx8T);
        pq_p2<<<1024, 256, SMEM_BYTES, stream>>>(
            (const ushort_t*)xbf, (const uint4*)vbf, idx8T, slab);
        pq_p3<<<(BATCH * OUT_DIM / 4 + 255) / 256, 256, 0, stream>>>(slab, bias, out);
    }
}

// Round 5
// 113.187 us; speedup vs baseline: 3.1054x; 3.1054x over previous
//
#include <hip/hip_runtime.h>

#define IN_DIM  4096
#define OUT_DIM 11008
#define NSUB    1376
#define KSQ     256
#define DSUB    8
#define BATCH   32

#define DTILE   8                    // subspaces per block
#define NTILE   64                   // output cols per block
#define KC      64                   // k per chunk
#define KSPLIT  8                    // k-blocks per output column
#define KPB     (IN_DIM / KSPLIT)    // 512
#define NCHUNK  4                    // chunks per half (2 halves of 256 k)
#define NBLK    (OUT_DIM / NTILE)    // 172
#define NBLKP   176                  // padded: 8 XCDs * 22
#define NPX     (NBLKP / 8)          // 22 nblk per XCD
#define GRID_MAIN (NBLKP * KSPLIT)   // 1408

typedef unsigned short ushort_t;
typedef unsigned int   uint_t;
typedef unsigned char  uchar_t;
typedef __attribute__((ext_vector_type(8))) short bf16x8;
typedef __attribute__((ext_vector_type(4))) float f32x4;

// workspace layout (bytes)
#define VEC_N    (NSUB * KSQ * DSUB)              // 2818048 floats
#define XBF_OFF  (VEC_N * 2)                      // 5636096  : xbf (bf16 x)
#define IDXT_OFF (XBF_OFF + BATCH * IN_DIM * 2)   // 5898240  : idx8T [NSUB][IN_DIM] u8
#define SLAB_OFF (IDXT_OFF + NSUB * IN_DIM)       // 11534336 : f32 slabs [KSPLIT][BATCH][OUT_DIM]
#define PREP_V   (VEC_N / 2)                      // 1409024 uints (2 bf16 each)
#define PREP_X   (BATCH * IN_DIM / 2)             // 65536
#define PREP_N   (PREP_V + PREP_X)                // 1474560 = 5760 * 256
#define PACK_BLK (PREP_N / 256)                   // 5760
#define IDXT_BLK ((IN_DIM / 128) * (NSUB / 32))   // 1376

__device__ __forceinline__ ushort_t f2bf(float f) {
    union { float f; uint_t u; } a; a.f = f;
    uint_t u = a.u;
    u += 0x7fffu + ((u >> 16) & 1u);   // round-to-nearest-even
    return (ushort_t)(u >> 16);
}

// ---- prep: bf16-pack codebook + x, AND transpose idx -> u8 [d][k] ---------
__global__ __launch_bounds__(256) void pq_prep(
    const float* __restrict__ x, const float* __restrict__ vecs,
    const int* __restrict__ idx,
    uint_t* __restrict__ vbf, uint_t* __restrict__ xbf,
    uchar_t* __restrict__ idx8T)
{
    __shared__ uchar_t sT[32][144];
    const int t = threadIdx.x;

    if (blockIdx.x < PACK_BLK) {
        int tid = blockIdx.x * 256 + t;
        if (tid < PREP_V) {
            float2 v = ((const float2*)vecs)[tid];
            vbf[tid] = (uint_t)f2bf(v.x) | ((uint_t)f2bf(v.y) << 16);
        } else {
            int i = tid - PREP_V;
            float2 v = ((const float2*)x)[i];
            xbf[i] = (uint_t)f2bf(v.x) | ((uint_t)f2bf(v.y) << 16);
        }
        return;
    }

    // idx transpose path
    const int bid = blockIdx.x - PACK_BLK;
    const int k0 = (bid & 31) * 128, d0 = (bid >> 5) * 32;
    #pragma unroll
    for (int p = 0; p < 16; ++p) {
        int f = p * 256 + t;           // 0..4095
        int kk = f >> 5, dd = f & 31;
        sT[dd][kk] = (uchar_t)idx[(size_t)(k0 + kk) * NSUB + d0 + dd];
    }
    __syncthreads();
    int dd = t >> 3, seg = t & 7;
    uint4 v = *(const uint4*)&sT[dd][seg * 16];
    *(uint4*)&idx8T[(size_t)(d0 + dd) * IN_DIM + k0 + seg * 16] = v;
}

// ---- main: barrier-free, wave-independent PQ-GEMM -------------------------
//
// Grid decode puts ALL 8 k-blocks of one nblk on the SAME XCD (assuming
// dispatch round-robins blockIdx%8 across XCDs): the 32 KB codebook slice is
// staged 8x but 7 of those hit that XCD's L2. K=512 per block, processed as
// 2 halves of 256 k, each with a full A[2][8] register preload (64 VGPR,
// fits under the launch_bounds 128-VGPR cap). Inner loop verbatim from the
// round-2 kernel (3x harness-verified).
__global__ __launch_bounds__(256, 4) void pq_main(
    const ushort_t* __restrict__ xbfu, const uint4* __restrict__ vbf4,
    const uchar_t* __restrict__ idx8T, float* __restrict__ slab)
{
    __shared__ uint4  sV4[4 * 512];        // 32 KB: per-wave 2x256 codewords
    __shared__ uint_t sW32[4 * 16 * 32];   //  8 KB: per-wave 16 rows x 64 k (swizzled)

    const int id  = blockIdx.x;
    const int xcd = id & 7;
    const int s   = id >> 3;               // 0..175
    const int nblk = xcd * NPX + (s % NPX);
    const int kblk = s / NPX;              // 0..7
    if (nblk >= NBLK) return;

    const int t    = threadIdx.x;
    const int w    = t >> 6;
    const int lane = t & 63;
    const int d0   = nblk * DTILE;
    const int kbase = kblk * KPB;

    const int l15 = lane & 15;
    const int l4  = lane >> 4;
    const int dl  = lane >> 5;             // 0..1 : subspace within wave
    const int q   = lane & 31;             // 0..31 : k-pair within chunk

    // --- stage codebook slice (wave-disjoint rows), two 4-batch rounds
    {
        const size_t src0 = (size_t)(d0 + w * 2) * KSQ;   // uint4 units
        #pragma unroll
        for (int h = 0; h < 2; ++h) {
            uint4 vst[4];
            #pragma unroll
            for (int p = 0; p < 4; ++p)
                vst[p] = vbf4[src0 + (h * 4 + p) * 64 + lane];
            #pragma unroll
            for (int p = 0; p < 4; ++p)
                sV4[w * 512 + (h * 4 + p) * 64 + lane] = vst[p];
        }
    }

    f32x4 acc[2];
    acc[0] = (f32x4)0.0f; acc[1] = (f32x4)0.0f;

    const uchar_t* idxrow = idx8T + (size_t)(d0 + w * 2 + dl) * IN_DIM + kbase;
    const int vbase = w * 512 + dl * 256;
    const int Rbase = (w * 16 + dl * 8) * 32;   // dword base of this lane's 8 rows

    #pragma unroll
    for (int h = 0; h < 2; ++h) {
        const int kh = kbase + h * 256;

        // --- A fragments for this 256-k half (16 x b128 = 64 VGPR)
        bf16x8 A[2][8];
        #pragma unroll
        for (int mt = 0; mt < 2; ++mt)
            #pragma unroll
            for (int kk = 0; kk < 8; ++kk)
                A[mt][kk] = *(const bf16x8*)
                    &xbfu[(size_t)(mt * 16 + l15) * IN_DIM + kh + kk * 32 + l4 * 8];

        // --- idx bytes for this half (4 x ushort)
        uint_t bb[NCHUNK];
        #pragma unroll
        for (int c = 0; c < NCHUNK; ++c)
            bb[c] = *(const ushort_t*)&idxrow[h * 256 + c * KC + q * 2];

        __builtin_amdgcn_sched_barrier(0);   // keep preloads above the chunks

        #pragma unroll
        for (int c = 0; c < NCHUNK; ++c) {
            uint4 g0 = sV4[vbase + (bb[c] & 255)];
            uint4 g1 = sV4[vbase + (bb[c] >> 8)];

            // transpose 2x8 -> 8 b32 writes; xor-swizzle 16B units with row (=j)
            #pragma unroll
            for (int j = 0; j < 8; ++j) {
                const uint_t sel = (j & 1) ? 0x07060302u : 0x05040100u;
                uint_t a0 = (j >> 1) == 0 ? g0.x : (j >> 1) == 1 ? g0.y : (j >> 1) == 2 ? g0.z : g0.w;
                uint_t a1 = (j >> 1) == 0 ? g1.x : (j >> 1) == 1 ? g1.y : (j >> 1) == 2 ? g1.z : g1.w;
                uint_t wv = __builtin_amdgcn_perm(a1, a0, sel);   // [k even | k odd<<16]
                int dw = ((((q >> 2) ^ j) << 2) | (q & 3));
                sW32[Rbase + j * 32 + dw] = wv;
            }

            // B read (swizzled) + MFMA
            #pragma unroll
            for (int kq = 0; kq < 2; ++kq) {
                int u16 = (kq * 4 + l4) ^ (l15 & 7);
                bf16x8 B = *(const bf16x8*)
                    ((const char*)sW32 + (w * 16 + l15) * 128 + u16 * 16);
                #pragma unroll
                for (int mt = 0; mt < 2; ++mt)
                    acc[mt] = __builtin_amdgcn_mfma_f32_16x16x32_bf16(
                        A[mt][c * 2 + kq], B, acc[mt], 0, 0, 0);
            }
        }
    }

    // --- dense store to this kblk's slab (no atomics)
    float* sl = slab + (size_t)kblk * BATCH * OUT_DIM;
    const int col = nblk * NTILE + w * 16 + l15;
    #pragma unroll
    for (int mt = 0; mt < 2; ++mt)
        #pragma unroll
        for (int r = 0; r < 4; ++r)
            sl[(size_t)(mt * 16 + l4 * 4 + r) * OUT_DIM + col] = acc[mt][r];
}

// ---- reduce: out = bias + sum_k slabs -------------------------------------
__global__ __launch_bounds__(256) void pq_reduce(
    const float* __restrict__ slab, const float* __restrict__ bias,
    float* __restrict__ out)
{
    int i = blockIdx.x * 256 + threadIdx.x;        // < 88064
    int m = i / (OUT_DIM / 4), n4 = i - m * (OUT_DIM / 4);
    float4 s = ((const float4*)bias)[n4];
    #pragma unroll
    for (int kb = 0; kb < KSPLIT; ++kb) {
        float4 v = ((const float4*)slab)[(size_t)(kb * BATCH + m) * (OUT_DIM / 4) + n4];
        s.x += v.x; s.y += v.y; s.z += v.z; s.w += v.w;
    }
    ((float4*)out)[(size_t)m * (OUT_DIM / 4) + n4] = s;
}

extern "C" void kernel_launch(void* const* d_in, const int* in_sizes, int n_in,
                              void* d_out, int out_size, void* d_ws, size_t ws_size,
                              hipStream_t stream) {
    const float* x    = (const float*)d_in[0];
    const float* vecs = (const float*)d_in[1];
    const float* bias = (const float*)d_in[2];
    const int*   idx  = (const int*)d_in[3];
    float* out = (float*)d_out;

    uint_t*  vbf   = (uint_t*)d_ws;
    uint_t*  xbf   = (uint_t*)((char*)d_ws + XBF_OFF);
    uchar_t* idx8T = (uchar_t*)((char*)d_ws + IDXT_OFF);
    float*   slab  = (float*)((char*)d_ws + SLAB_OFF);

    pq_prep<<<PACK_BLK + IDXT_BLK, 256, 0, stream>>>(x, vecs, idx, vbf, xbf, idx8T);
    pq_main<<<GRID_MAIN, 256, 0, stream>>>(
        (const ushort_t*)xbf, (const uint4*)vbf, idx8T, slab);
    pq_reduce<<<(BATCH * OUT_DIM / 4) / 256, 256, 0, stream>>>(slab, bias, out);
}